// Round 11
// baseline (1286.886 us; speedup 1.0000x reference)
//
#include <hip/hip_runtime.h>

// Problem constants (fixed shapes from setup_inputs)
constexpr int B  = 4;
constexpr int N  = 16384;   // dense points
constexpr int S  = 4096;    // sparse points
constexpr int CD = 128;     // dense feature channels
constexpr int CS = 256;     // sparse feature channels
constexpr int CO = 128;     // output channels
constexpr int CIN = CD + CS; // 384

// Spatial grid. N(0,1) data: |coord| < ~4.8 << 6.5, nothing clamps.
constexpr int   G    = 40;
constexpr int   G3   = G * G * G;        // 64000 cells
constexpr float GLO  = -6.5f;
constexpr float GH   = 13.0f / 40.0f;    // 0.325
constexpr float GINV = 1.0f / GH;

__device__ __forceinline__ int cell1(float x) {
  int c = (int)floorf((x - GLO) * GINV);
  return min(max(c, 0), G - 1);
}

// Lexicographic (t, idx) top-3 insert — proven in R9/R10 to match reference
// selection; makes results independent of candidate arrival order.
__device__ __forceinline__ bool lex_lt(float x, int sg, float d, int i) {
  return (x < d) | ((x == d) & (sg < i));
}
__device__ __forceinline__ void insert3lex(float& d0, float& d1, float& d2,
                                           int& i0, int& i1, int& i2,
                                           float x, int sg) {
  const bool lt2 = lex_lt(x, sg, d2, i2);
  const bool lt1 = lex_lt(x, sg, d1, i1);
  const bool lt0 = lex_lt(x, sg, d0, i0);
  i2 = lt1 ? i1 : (lt2 ? sg : i2);
  i1 = lt0 ? i0 : (lt1 ? sg : i1);
  i0 = lt0 ? sg : i0;
  d2 = fminf(fmaxf(x, d1), d2);
  d1 = __builtin_amdgcn_fmed3f(x, d0, d1);
  d0 = fminf(x, d0);
}

// ---------------------------------------------------------------------------
// B1: histograms.
// ---------------------------------------------------------------------------
__global__ __launch_bounds__(256) void count_s_kernel(
    const float* __restrict__ sxyz, unsigned* __restrict__ cnt) {
  const int gid = blockIdx.x * 256 + threadIdx.x;
  const int b = gid >> 12;
  const int s = gid & (S - 1);
  const float sx = sxyz[b * 3 * S + s];
  const float sy = sxyz[b * 3 * S + S + s];
  const float sz = sxyz[b * 3 * S + 2 * S + s];
  atomicAdd(&cnt[b * G3 + (cell1(sz) * G + cell1(sy)) * G + cell1(sx)], 1u);
}

__global__ __launch_bounds__(256) void count_d_kernel(
    const float* __restrict__ dxyz, unsigned* __restrict__ cnt) {
  const int gid = blockIdx.x * 256 + threadIdx.x;
  const int b = gid >> 14;
  const int n = gid & (N - 1);
  const float x = dxyz[b * 3 * N + n];
  const float y = dxyz[b * 3 * N + N + n];
  const float z = dxyz[b * 3 * N + 2 * N + n];
  atomicAdd(&cnt[b * G3 + (cell1(z) * G + cell1(y)) * G + cell1(x)], 1u);
}

// ---------------------------------------------------------------------------
// B2: DETERMINISTIC per-batch exclusive prefix scan (this is the R10 bug fix:
// atomic allocation gave randomly-ordered cell groups, so "sorted" points
// were not spatially contiguous). Blocks 0..B-1: sparse; B..2B-1: dense.
// ---------------------------------------------------------------------------
constexpr int SCAN_T = 1024;
constexpr int SCAN_C = (G3 + SCAN_T - 1) / SCAN_T;  // 63

__global__ __launch_bounds__(1024) void scan_kernel(
    const unsigned* __restrict__ cnt_s, const unsigned* __restrict__ cnt_d,
    uint2* __restrict__ cellrange, unsigned* __restrict__ cur_s,
    unsigned* __restrict__ cur_d) {
  const int which = blockIdx.x / B;  // 0 = sparse, 1 = dense
  const int b = blockIdx.x - which * B;
  const unsigned* __restrict__ C = (which ? cnt_d : cnt_s) + b * G3;
  const int t = threadIdx.x;
  const int lo = t * SCAN_C;
  const int hi = min(lo + SCAN_C, G3);
  unsigned mysum = 0;
  for (int i = lo; i < hi; ++i) mysum += C[i];
  __shared__ unsigned part[SCAN_T];
  part[t] = mysum;
  __syncthreads();
  for (int off = 1; off < SCAN_T; off <<= 1) {
    unsigned v = (t >= off) ? part[t - off] : 0u;
    __syncthreads();
    part[t] += v;
    __syncthreads();
  }
  unsigned run = part[t] - mysum;
  if (which == 0) {
    uint2* CRo = cellrange + b * G3;
    unsigned* cu = cur_s + b * G3;
    for (int i = lo; i < hi; ++i) {
      const unsigned c = C[i];
      CRo[i] = make_uint2(run, c);
      cu[i] = run;
      run += c;
    }
  } else {
    unsigned* cu = cur_d + b * G3;
    for (int i = lo; i < hi; ++i) { cu[i] = run; run += C[i]; }
  }
}

// ---------------------------------------------------------------------------
// B3s: scatter sparse into cell-ordered buckets; premultiplied coords
// (EXACT R7/R9 expression -> bit-identical t) + original index.
// ---------------------------------------------------------------------------
__global__ __launch_bounds__(256) void scatter_s_kernel(
    const float* __restrict__ sxyz, unsigned* __restrict__ cur_s,
    int* __restrict__ sortedS, float4* __restrict__ sortedQ) {
  const int gid = blockIdx.x * 256 + threadIdx.x;
  const int b = gid >> 12;
  const int s = gid & (S - 1);
  const float sx = sxyz[b * 3 * S + s];
  const float sy = sxyz[b * 3 * S + S + s];
  const float sz = sxyz[b * 3 * S + 2 * S + s];
  const int cid = (cell1(sz) * G + cell1(sy)) * G + cell1(sx);
  const unsigned pos = atomicAdd(&cur_s[b * G3 + cid], 1u);
  sortedS[b * S + pos] = s;
  sortedQ[b * S + pos] = make_float4(-2.f * sx, -2.f * sy, -2.f * sz,
                                     fmaf(sx, sx, fmaf(sy, sy, sz * sz)));
}

// ---------------------------------------------------------------------------
// B3d: scatter dense into cell-ordered positions: (x, y, z, n_as_bits).
// ---------------------------------------------------------------------------
__global__ __launch_bounds__(256) void scatter_d_kernel(
    const float* __restrict__ dxyz, unsigned* __restrict__ cur_d,
    float4* __restrict__ sortedDQ) {
  const int gid = blockIdx.x * 256 + threadIdx.x;
  const int b = gid >> 14;
  const int n = gid & (N - 1);
  const float x = dxyz[b * 3 * N + n];
  const float y = dxyz[b * 3 * N + N + n];
  const float z = dxyz[b * 3 * N + 2 * N + n];
  const int cid = (cell1(z) * G + cell1(y)) * G + cell1(x);
  const unsigned pos = atomicAdd(&cur_d[b * G3 + cid], 1u);
  sortedDQ[b * N + pos] = make_float4(x, y, z, __int_as_float(n));
}

// ---------------------------------------------------------------------------
// K1: block-cooperative exact KNN. 128 threads = 128 spatially-contiguous
// dense points. Loop: cooperatively append the next ring-shell of sparse
// candidates (around the block's cell-bbox) into LDS, then every thread
// scans the new LDS range with wave-uniform broadcast reads (the R5/R7
// execution pattern that measured 88-100% VALUBusy). A point is certified
// exact when (d2+n2)*1.001+1e-4 <= margin^2, margin = distance to the
// nearest un-loaded region face (grid-clipped faces = infinite). LDS
// overflow -> in-kernel brute scan over all S (exact, rare).
// ---------------------------------------------------------------------------
constexpr int KT  = 128;   // threads per block
constexpr int CAP = 2048;  // LDS candidate capacity

__global__ __launch_bounds__(KT) void knn_tile_kernel(
    const float4* __restrict__ sortedDQ, const float* __restrict__ sxyz,
    const uint2* __restrict__ cellrange, const int* __restrict__ sortedS,
    const float4* __restrict__ sortedQ, float* __restrict__ wgt,
    int* __restrict__ idx) {
  __shared__ float4 q_s[CAP];
  __shared__ int    s_s[CAP];
  __shared__ int    scan_s[KT];
  __shared__ int    bb[6];
  __shared__ int    flags[2];  // [0]=all-exact, [1]=overflow

  const int tid = threadIdx.x;
  const int b = blockIdx.y;
  const int gid = b * N + blockIdx.x * KT + tid;
  const float4 dq = sortedDQ[gid];  // coalesced
  const float bx = dq.x, by = dq.y, bz = dq.z;
  const int n = __float_as_int(dq.w);
  const float n2 = bx * bx + by * by + bz * bz;
  const int cx = cell1(bx), cy = cell1(by), cz = cell1(bz);

  if (tid == 0) {
    bb[0] = cx; bb[1] = cx; bb[2] = cy; bb[3] = cy; bb[4] = cz; bb[5] = cz;
  }
  __syncthreads();
  atomicMin(&bb[0], cx); atomicMax(&bb[1], cx);
  atomicMin(&bb[2], cy); atomicMax(&bb[3], cy);
  atomicMin(&bb[4], cz); atomicMax(&bb[5], cz);
  __syncthreads();
  const int bxlo = bb[0], bxhi = bb[1];
  const int bylo = bb[2], byhi = bb[3];
  const int bzlo = bb[4], bzhi = bb[5];

  const uint2* __restrict__ CR = cellrange + b * G3;
  const int* __restrict__ SS = sortedS + b * S;
  const float4* __restrict__ Q = sortedQ + b * S;

  float d0 = 1e30f, d1 = 1e30f, d2 = 1e30f;
  int i0 = 0, i1 = 0, i2 = 0;
  int count = 0;
  bool brute = false;

  for (int rr = 1; rr <= G; ++rr) {
    const int xlo = max(bxlo - rr, 0), xhi = min(bxhi + rr, G - 1);
    const int ylo = max(bylo - rr, 0), yhi = min(byhi + rr, G - 1);
    const int zlo = max(bzlo - rr, 0), zhi = min(bzhi + rr, G - 1);
    const int pxlo = max(bxlo - rr + 1, 0), pxhi = min(bxhi + rr - 1, G - 1);
    const int pylo = max(bylo - rr + 1, 0), pyhi = min(byhi + rr - 1, G - 1);
    const int pzlo = max(bzlo - rr + 1, 0), pzhi = min(bzhi + rr - 1, G - 1);
    const int X = xhi - xlo + 1, Y = yhi - ylo + 1, Z = zhi - zlo + 1;
    const int total = X * Y * Z;

    // count candidates in my share of the new shell's cells
    int mycnt = 0;
    for (int u = tid; u < total; u += KT) {
      const int ax = xlo + u % X;
      const int ay = ylo + (u / X) % Y;
      const int az = zlo + u / (X * Y);
      if (rr > 1 && ax >= pxlo && ax <= pxhi && ay >= pylo && ay <= pyhi &&
          az >= pzlo && az <= pzhi) continue;
      mycnt += (int)CR[(az * G + ay) * G + ax].y;
    }
    scan_s[tid] = mycnt;
    __syncthreads();
    for (int off = 1; off < KT; off <<= 1) {
      int v = (tid >= off) ? scan_s[tid - off] : 0;
      __syncthreads();
      scan_s[tid] += v;
      __syncthreads();
    }
    const int newTotal = scan_s[KT - 1];
    int base = count + scan_s[tid] - mycnt;
    if (tid == 0) flags[1] = (count + newTotal > CAP);
    __syncthreads();
    if (flags[1]) { brute = true; break; }

    // cooperative copy of the shell into LDS (global reads contiguous/cell)
    for (int u = tid; u < total; u += KT) {
      const int ax = xlo + u % X;
      const int ay = ylo + (u / X) % Y;
      const int az = zlo + u / (X * Y);
      if (rr > 1 && ax >= pxlo && ax <= pxhi && ay >= pylo && ay <= pyhi &&
          az >= pzlo && az <= pzhi) continue;
      const uint2 rc = CR[(az * G + ay) * G + ax];
      for (unsigned k = 0; k < rc.y; ++k) {
        q_s[base] = Q[rc.x + k];
        s_s[base] = SS[rc.x + k];
        ++base;
      }
    }
    __syncthreads();

    // every thread scans the NEW candidates (wave-uniform LDS broadcast)
    for (int j = count; j < count + newTotal; ++j) {
      const float4 q = q_s[j];
      const int sg = s_s[j];
      const float x = fmaf(q.x, bx, fmaf(q.y, by, fmaf(q.z, bz, q.w)));
      insert3lex(d0, d1, d2, i0, i1, i2, x, sg);
    }
    count += newTotal;

    // exactness: margin to nearest un-loaded face (clipped face = +inf)
    float mx = 1e30f;
    if (xlo > 0)     mx = fminf(mx, bx - (GLO + xlo * GH));
    if (xhi < G - 1) mx = fminf(mx, (GLO + (xhi + 1) * GH) - bx);
    if (ylo > 0)     mx = fminf(mx, by - (GLO + ylo * GH));
    if (yhi < G - 1) mx = fminf(mx, (GLO + (yhi + 1) * GH) - by);
    if (zlo > 0)     mx = fminf(mx, bz - (GLO + zlo * GH));
    if (zhi < G - 1) mx = fminf(mx, (GLO + (zhi + 1) * GH) - bz);
    const bool exact = fmaf(d2 + n2, 1.001f, 1e-4f) <= mx * mx;
    if (tid == 0) flags[0] = 1;
    __syncthreads();
    if (!exact) atomicAnd(&flags[0], 0);
    __syncthreads();
    if (flags[0]) break;
  }

  if (brute) {  // exact fallback: uniform-broadcast scan of all S
    d0 = d1 = d2 = 1e30f;
    i0 = i1 = i2 = 0;
    for (int j = 0; j < S; ++j) {
      const float4 q = Q[j];
      const int sg = SS[j];
      const float x = fmaf(q.x, bx, fmaf(q.y, by, fmaf(q.z, bz, q.w)));
      insert3lex(d0, d1, d2, i0, i1, i2, x, sg);
    }
  }

  // ---- weights: reference's expanded form (unchanged, passing) ----
  int ii[3] = {i0, i1, i2};
  float w[3];
  #pragma unroll
  for (int k = 0; k < 3; ++k) {
    const float sx = sxyz[b * 3 * S + ii[k]];
    const float sy = sxyz[b * 3 * S + S + ii[k]];
    const float sz = sxyz[b * 3 * S + 2 * S + ii[k]];
    const float s2 = sx * sx + sy * sy + sz * sz;
    const float inner = bx * sx + by * sy + bz * sz;
    const float d = fmaxf((n2 + s2) - 2.f * inner, 0.f);
    w[k] = 1.f / (d + 1e-8f);
  }
  const float inv = 1.f / (w[0] + w[1] + w[2]);
  const size_t base = ((size_t)b * N + n) * 3;
  wgt[base + 0] = w[0] * inv;
  wgt[base + 1] = w[1] * inv;
  wgt[base + 2] = w[2] * inv;
  idx[base + 0] = ii[0];
  idx[base + 1] = ii[1];
  idx[base + 2] = ii[2];
}

// ---------------------------------------------------------------------------
// K1c: transpose conv_w -> Wt[c][o] for zproj's uniform loads.
// ---------------------------------------------------------------------------
__global__ __launch_bounds__(256) void wtrans_kernel(
    const float* __restrict__ cw, float* __restrict__ wt) {
  const int i = blockIdx.x * 256 + threadIdx.x;
  const int o = i / CIN;
  const int c = i - o * CIN;
  wt[c * CO + o] = cw[i];
}

// ---------------------------------------------------------------------------
// K2: Z[b, s, o] = sum_c Ws[o, c] * sparse_data[b, c, s]   (o-contiguous!)
// ---------------------------------------------------------------------------
__global__ __launch_bounds__(64) void zproj_kernel(
    const float* __restrict__ sdata, const float* __restrict__ wt,
    float* __restrict__ Z) {
  const int b = blockIdx.z;
  const int og = blockIdx.y;
  const int s = blockIdx.x * 64 + threadIdx.x;
  const float* __restrict__ xp = sdata + b * CS * S + s;
  const float* __restrict__ wp = wt + CD * CO + og * 16;

  float acc[16];
  #pragma unroll
  for (int i = 0; i < 16; ++i) acc[i] = 0.f;

  #pragma unroll 4
  for (int c = 0; c < CS; ++c) {
    const float xv = xp[c * S];
    #pragma unroll
    for (int i = 0; i < 16; ++i)
      acc[i] = fmaf(wp[c * CO + i], xv, acc[i]);
  }

  float4* zp = reinterpret_cast<float4*>(Z + (b * S + s) * CO + og * 16);
  #pragma unroll
  for (int i = 0; i < 4; ++i)
    zp[i] = make_float4(acc[4*i+0], acc[4*i+1], acc[4*i+2], acc[4*i+3]);
}

// ---------------------------------------------------------------------------
// K3: y[b, o, n] = sum_c Wd[o,c]*dense_data[b,c,n] + sum_k w_k * Z[b,idx_k,o]
// ---------------------------------------------------------------------------
__global__ __launch_bounds__(256) void ygemm_kernel(
    const float* __restrict__ ddata, const float* __restrict__ cw,
    const float* __restrict__ Z, const float* __restrict__ wgt,
    const int* __restrict__ idx, float* __restrict__ y) {
  const int b = blockIdx.y;
  const int n = blockIdx.x * 64 + (threadIdx.x & 63);
  const int rg = __builtin_amdgcn_readfirstlane(threadIdx.x >> 6);
  const float* __restrict__ xp = ddata + b * CD * N + n;
  const float* __restrict__ wp = cw + rg * 32 * CIN;

  float acc[32];
  #pragma unroll
  for (int i = 0; i < 32; ++i) acc[i] = 0.f;

  #pragma unroll 4
  for (int c = 0; c < CD; ++c) {
    const float xv = xp[c * N];
    #pragma unroll
    for (int i = 0; i < 32; ++i)
      acc[i] = fmaf(wp[i * CIN + c], xv, acc[i]);
  }

  const int pb = (b * N + n) * 3;
  #pragma unroll
  for (int k = 0; k < 3; ++k) {
    const float wk = wgt[pb + k];
    const int ik = idx[pb + k];
    const float4* zp =
        reinterpret_cast<const float4*>(Z + (b * S + ik) * CO + rg * 32);
    #pragma unroll
    for (int i = 0; i < 8; ++i) {
      float4 zv = zp[i];
      acc[4*i+0] = fmaf(wk, zv.x, acc[4*i+0]);
      acc[4*i+1] = fmaf(wk, zv.y, acc[4*i+1]);
      acc[4*i+2] = fmaf(wk, zv.z, acc[4*i+2]);
      acc[4*i+3] = fmaf(wk, zv.w, acc[4*i+3]);
    }
  }

  float* yp = y + b * CO * N + (rg * 32) * N + n;
  #pragma unroll
  for (int i = 0; i < 32; ++i) yp[i * N] = acc[i];
}

// ---------------------------------------------------------------------------
// K4: per-channel sum / sumsq over (B, N).
// ---------------------------------------------------------------------------
__global__ __launch_bounds__(256) void stats_kernel(
    const float* __restrict__ y, float* __restrict__ stats) {
  const int o = blockIdx.x;
  const int b = blockIdx.y;
  const float4* yp = reinterpret_cast<const float4*>(y + (b * CO + o) * N);
  float s = 0.f, sq = 0.f;
  for (int j = threadIdx.x; j < N / 4; j += 256) {
    float4 v = yp[j];
    s  += v.x + v.y + v.z + v.w;
    sq += v.x * v.x + v.y * v.y + v.z * v.z + v.w * v.w;
  }
  __shared__ float ls[256];
  __shared__ float lq[256];
  ls[threadIdx.x] = s;
  lq[threadIdx.x] = sq;
  __syncthreads();
  for (int st = 128; st > 0; st >>= 1) {
    if (threadIdx.x < (unsigned)st) {
      ls[threadIdx.x] += ls[threadIdx.x + st];
      lq[threadIdx.x] += lq[threadIdx.x + st];
    }
    __syncthreads();
  }
  if (threadIdx.x == 0) {
    atomicAdd(&stats[o], ls[0]);
    atomicAdd(&stats[CO + o], lq[0]);
  }
}

// ---------------------------------------------------------------------------
// K4b: fold BN stats into per-channel scale/shift.
// ---------------------------------------------------------------------------
__global__ void scaleshift_kernel(const float* __restrict__ stats,
                                  const float* __restrict__ gamma,
                                  const float* __restrict__ beta,
                                  float* __restrict__ ss) {
  const int o = threadIdx.x;
  const float invc = 1.f / (float)(B * N);
  const float m = stats[o] * invc;
  float v = stats[CO + o] * invc - m * m;
  v = fmaxf(v, 0.f);
  const float sc = gamma[o] / sqrtf(v + 1e-5f);
  ss[o] = sc;
  ss[CO + o] = beta[o] - m * sc;
}

// ---------------------------------------------------------------------------
// K5: in-place normalize + LeakyReLU(0.2) on d_out's y region (float4).
// ---------------------------------------------------------------------------
__global__ __launch_bounds__(256) void norm_kernel(float* __restrict__ y,
                                                   const float* __restrict__ ss) {
  const int i = blockIdx.x * 256 + threadIdx.x;
  const int o = (i >> 12) & (CO - 1);
  const float sc = ss[o];
  const float sh = ss[CO + o];
  float4* yp = reinterpret_cast<float4*>(y);
  float4 v = yp[i];
  float t;
  t = fmaf(v.x, sc, sh); v.x = fmaxf(t, 0.2f * t);
  t = fmaf(v.y, sc, sh); v.y = fmaxf(t, 0.2f * t);
  t = fmaf(v.z, sc, sh); v.z = fmaxf(t, 0.2f * t);
  t = fmaf(v.w, sc, sh); v.w = fmaxf(t, 0.2f * t);
  yp[i] = v;
}

// ---------------------------------------------------------------------------
extern "C" void kernel_launch(void* const* d_in, const int* in_sizes, int n_in,
                              void* d_out, int out_size, void* d_ws, size_t ws_size,
                              hipStream_t stream) {
  const float* dxyz  = (const float*)d_in[0];
  const float* sxyz  = (const float*)d_in[1];
  const float* ddata = (const float*)d_in[2];
  const float* sdata = (const float*)d_in[3];
  const float* cw    = (const float*)d_in[4];
  const float* gamma = (const float*)d_in[5];
  const float* beta  = (const float*)d_in[6];
  float* out = (float*)d_out;

  char* wsb = (char*)d_ws;
  // Persistent: wgt/idx. Binning scratch aliases the Z region (dead before
  // zproj writes Z). Total footprint: 14,157,824 B (unchanged).
  float*    wgt      = (float*)   (wsb);               //   786,432 B
  int*      idxb     = (int*)     (wsb + 786432);      //   786,432 B
  float*    Z        = (float*)   (wsb + 1572864);     // 8,388,608 B
  uint2*    cellrange= (uint2*)   (wsb + 1572864);     // 2,048,000
  unsigned* cnt_s    = (unsigned*)(wsb + 3620864);     // 1,024,000
  unsigned* cnt_d    = (unsigned*)(wsb + 4644864);     // 1,024,000
  unsigned* cur_s    = (unsigned*)(wsb + 5668864);     // 1,024,000
  unsigned* cur_d    = (unsigned*)(wsb + 6692864);     // 1,024,000
  int*      sortedS  = (int*)     (wsb + 7716864);     // 65,536
  float4*   sortedQ  = (float4*)  (wsb + 7782400);     // 262,144
  float4*   sortedDQ = (float4*)  (wsb + 8044544);     // 1,048,576 -> 9,093,120
  float*    wt       = (float*)   (wsb + 9961472);     // 196,608
  float*    stats    = (float*)   (wsb + 14155776);    // 1,024
  float*    ss       = (float*)   (wsb + 14156800);    // 1,024

  hipMemsetAsync(stats, 0, 2 * CO * sizeof(float), stream);
  hipMemsetAsync(cnt_s, 0, 2 * 1024000, stream);  // cnt_s + cnt_d (contiguous)

  count_s_kernel <<<B * S / 256, 256, 0, stream>>>(sxyz, cnt_s);
  count_d_kernel <<<B * N / 256, 256, 0, stream>>>(dxyz, cnt_d);
  scan_kernel    <<<2 * B, SCAN_T, 0, stream>>>(cnt_s, cnt_d, cellrange,
                                                cur_s, cur_d);
  scatter_s_kernel<<<B * S / 256, 256, 0, stream>>>(sxyz, cur_s, sortedS, sortedQ);
  scatter_d_kernel<<<B * N / 256, 256, 0, stream>>>(dxyz, cur_d, sortedDQ);
  knn_tile_kernel<<<dim3(N / KT, B), KT, 0, stream>>>(sortedDQ, sxyz, cellrange,
                                                      sortedS, sortedQ, wgt, idxb);

  wtrans_kernel   <<<CO * CIN / 256, 256, 0, stream>>>(cw, wt);
  zproj_kernel    <<<dim3(S / 64, CO / 16, B), 64, 0, stream>>>(sdata, wt, Z);
  ygemm_kernel    <<<dim3(N / 64, B), 256, 0, stream>>>(ddata, cw, Z, wgt, idxb, out);
  stats_kernel    <<<dim3(CO, B), 256, 0, stream>>>(out, stats);
  scaleshift_kernel<<<1, 128, 0, stream>>>(stats, gamma, beta, ss);
  norm_kernel     <<<(B * CO * N / 4) / 256, 256, 0, stream>>>(out, ss);

  hipMemcpyAsync(out + (size_t)B * CO * N, dxyz, (size_t)B * 3 * N * sizeof(float),
                 hipMemcpyDeviceToDevice, stream);
}

// Round 12
// 404.903 us; speedup vs baseline: 3.1783x; 3.1783x over previous
//
#include <hip/hip_runtime.h>

// Problem constants (fixed shapes from setup_inputs)
constexpr int B  = 4;
constexpr int N  = 16384;   // dense points
constexpr int S  = 4096;    // sparse points
constexpr int CD = 128;     // dense feature channels
constexpr int CS = 256;     // sparse feature channels
constexpr int CO = 128;     // output channels
constexpr int CIN = CD + CS; // 384

// Radius binning. N(0,1)^3: rho < ~5.0 << 6.6.
constexpr int   RB    = 256;
constexpr float RBW   = 6.6f / 256.0f;
constexpr float RBINV = 256.0f / 6.6f;

__device__ __forceinline__ int rbin(float rho) {
  return min(RB - 1, (int)(rho * RBINV));
}

// Lexicographic (t, idx) top-3 insert — proven (R9-R11 pass) to match the
// reference selection and to be independent of candidate arrival order.
__device__ __forceinline__ bool lex_lt(float x, int sg, float d, int i) {
  return (x < d) | ((x == d) & (sg < i));
}
__device__ __forceinline__ void insert3lex(float& d0, float& d1, float& d2,
                                           int& i0, int& i1, int& i2,
                                           float x, int sg) {
  const bool lt2 = lex_lt(x, sg, d2, i2);
  const bool lt1 = lex_lt(x, sg, d1, i1);
  const bool lt0 = lex_lt(x, sg, d0, i0);
  i2 = lt1 ? i1 : (lt2 ? sg : i2);
  i1 = lt0 ? i0 : (lt1 ? sg : i1);
  i0 = lt0 ? sg : i0;
  d2 = fminf(fmaxf(x, d1), d2);
  d1 = __builtin_amdgcn_fmed3f(x, d0, d1);
  d0 = fminf(x, d0);
}

// ---------------------------------------------------------------------------
// R1: radius-bin histograms (sparse and dense).
// ---------------------------------------------------------------------------
__global__ __launch_bounds__(256) void rcount_s_kernel(
    const float* __restrict__ sxyz, unsigned* __restrict__ rcnt) {
  const int gid = blockIdx.x * 256 + threadIdx.x;  // = b*S + s
  const int b = gid >> 12;
  const int s = gid & (S - 1);
  const float sx = sxyz[b * 3 * S + s];
  const float sy = sxyz[b * 3 * S + S + s];
  const float sz = sxyz[b * 3 * S + 2 * S + s];
  const float s2 = fmaf(sx, sx, fmaf(sy, sy, sz * sz));
  atomicAdd(&rcnt[b * RB + rbin(sqrtf(s2))], 1u);
}

__global__ __launch_bounds__(256) void rcount_d_kernel(
    const float* __restrict__ dxyz, unsigned* __restrict__ rcnt) {
  const int gid = blockIdx.x * 256 + threadIdx.x;  // = b*N + n
  const int b = gid >> 14;
  const int n = gid & (N - 1);
  const float x = dxyz[b * 3 * N + n];
  const float y = dxyz[b * 3 * N + N + n];
  const float z = dxyz[b * 3 * N + 2 * N + n];
  const float n2 = x * x + y * y + z * z;
  atomicAdd(&rcnt[b * RB + rbin(sqrtf(n2))], 1u);
}

// ---------------------------------------------------------------------------
// R2: deterministic exclusive scan over 256 bins. blocks 0..B-1 sparse
// (writes rofs_s + rcur_s), B..2B-1 dense (writes rcur_d).
// ---------------------------------------------------------------------------
__global__ __launch_bounds__(256) void rscan_kernel(
    const unsigned* __restrict__ rcnt_s, const unsigned* __restrict__ rcnt_d,
    unsigned* __restrict__ rofs_s, unsigned* __restrict__ rcur_s,
    unsigned* __restrict__ rcur_d) {
  const int which = blockIdx.x >> 2;        // B = 4
  const int b = blockIdx.x & 3;
  const unsigned* __restrict__ C = (which ? rcnt_d : rcnt_s) + b * RB;
  const int t = threadIdx.x;
  __shared__ unsigned sc[RB];
  const unsigned v = C[t];
  sc[t] = v;
  __syncthreads();
  for (int off = 1; off < RB; off <<= 1) {
    unsigned u = (t >= off) ? sc[t - off] : 0u;
    __syncthreads();
    sc[t] += u;
    __syncthreads();
  }
  const unsigned ex = sc[t] - v;
  if (which == 0) { rofs_s[b * RB + t] = ex; rcur_s[b * RB + t] = ex; }
  else            { rcur_d[b * RB + t] = ex; }
}

// ---------------------------------------------------------------------------
// R3s: scatter sparse into rho-bin order; premultiplied coords (EXACT
// expression -> bit-identical t) + original index. Within-bin order is
// atomic-nondeterministic — harmless (lex insert).
// ---------------------------------------------------------------------------
__global__ __launch_bounds__(256) void rscatter_s_kernel(
    const float* __restrict__ sxyz, unsigned* __restrict__ rcur_s,
    int* __restrict__ sortedS, float4* __restrict__ sortedQ) {
  const int gid = blockIdx.x * 256 + threadIdx.x;
  const int b = gid >> 12;
  const int s = gid & (S - 1);
  const float sx = sxyz[b * 3 * S + s];
  const float sy = sxyz[b * 3 * S + S + s];
  const float sz = sxyz[b * 3 * S + 2 * S + s];
  const float s2 = fmaf(sx, sx, fmaf(sy, sy, sz * sz));
  const int bin = rbin(sqrtf(s2));
  const unsigned pos = atomicAdd(&rcur_s[b * RB + bin], 1u);
  sortedS[b * S + pos] = s;
  sortedQ[b * S + pos] = make_float4(-2.f * sx, -2.f * sy, -2.f * sz, s2);
}

// ---------------------------------------------------------------------------
// R3d: scatter dense into rho-bin order: (x, y, z, n_as_bits).
// ---------------------------------------------------------------------------
__global__ __launch_bounds__(256) void rscatter_d_kernel(
    const float* __restrict__ dxyz, unsigned* __restrict__ rcur_d,
    float4* __restrict__ sortedDQ) {
  const int gid = blockIdx.x * 256 + threadIdx.x;
  const int b = gid >> 14;
  const int n = gid & (N - 1);
  const float x = dxyz[b * 3 * N + n];
  const float y = dxyz[b * 3 * N + N + n];
  const float z = dxyz[b * 3 * N + 2 * N + n];
  const float n2 = x * x + y * y + z * z;
  const int bin = rbin(sqrtf(n2));
  const unsigned pos = atomicAdd(&rcur_d[b * RB + bin], 1u);
  sortedDQ[b * N + pos] = make_float4(x, y, z, __int_as_float(n));
}

// ---------------------------------------------------------------------------
// K1: exact KNN via adaptive 1D radius window over the rho-sorted sparse
// array. dist(p,s) >= |rho_p - rho_s|, so once the window's bin-edge
// clearance squared exceeds (d2+n2)*1.001+1e-4 on a side, that side is
// certified (bin edges bound unscanned same-bin elements; slack formula
// proven in R9-R11). Window expands in 256/side chunks: cooperative
// COALESCED stage into LDS, then a wave-uniform broadcast scan — the
// R5/R7 execution pattern that measured 88-100% VALUBusy. Exhausted side
// (lo==0 / hi==S) is trivially certified; worst case == brute scan.
// ---------------------------------------------------------------------------
constexpr int KT = 128;   // threads per block (= points per block)
constexpr int CH = 256;   // candidates staged per side per iteration

__global__ __launch_bounds__(KT) void knn_rho_kernel(
    const float4* __restrict__ sortedDQ, const float* __restrict__ sxyz,
    const unsigned* __restrict__ rofs_s, const int* __restrict__ sortedS,
    const float4* __restrict__ sortedQ, float* __restrict__ wgt,
    int* __restrict__ idx) {
  __shared__ float4 qs[2 * CH];
  __shared__ int    ss[2 * CH];
  __shared__ int    sh_start;
  __shared__ int    flags[2];

  const int tid = threadIdx.x;
  const int b = blockIdx.y;
  const float4 dq = sortedDQ[b * N + blockIdx.x * KT + tid];  // coalesced
  const float bx = dq.x, by = dq.y, bz = dq.z;
  const int n = __float_as_int(dq.w);
  const float n2 = bx * bx + by * by + bz * bz;
  const float rho_d = sqrtf(n2);

  if (tid == KT / 2)
    sh_start = (int)rofs_s[b * RB + rbin(rho_d)];
  __syncthreads();
  int lo = sh_start, hi = sh_start;

  const int* __restrict__ SS = sortedS + b * S;
  const float4* __restrict__ Q = sortedQ + b * S;

  float d0 = 1e30f, d1 = 1e30f, d2 = 1e30f;
  int i0 = 0, i1 = 0, i2 = 0;
  float edgeLo = 1e30f;   // until a lower chunk is staged, can't certify
  float edgeHi = -1e30f;
  bool lowDoneB = false, highDoneB = false;

  while (!(lowDoneB && highDoneB)) {
    const int stageLo = lowDoneB ? lo : max(lo - CH, 0);
    const int stageHi = highDoneB ? hi : min(hi + CH, S);
    const int c1 = lo - stageLo;
    const int c2 = stageHi - hi;
    const int tot = c1 + c2;

    for (int u = tid; u < tot; u += KT) {  // coalesced per side
      const int src = (u < c1) ? (stageLo + u) : (hi + (u - c1));
      qs[u] = Q[src];
      ss[u] = SS[src];
    }
    __syncthreads();

    for (int j = 0; j < tot; ++j) {  // wave-uniform LDS broadcast scan
      const float4 q = qs[j];
      const float x = fmaf(q.x, bx, fmaf(q.y, by, fmaf(q.z, bz, q.w)));
      insert3lex(d0, d1, d2, i0, i1, i2, x, ss[j]);
    }

    // bin-edge bounds for the unscanned regions (bound same-bin stragglers)
    if (c1 > 0)  // unscanned below are in bins <= bin(qs[0]) -> rho < ub
      edgeLo = (float)(rbin(sqrtf(qs[0].w)) + 1) * RBW;
    if (c2 > 0)  // unscanned above are in bins >= bin(qs[tot-1]) -> rho >= lb
      edgeHi = (float)rbin(sqrtf(qs[tot - 1].w)) * RBW;
    lo = stageLo;
    hi = stageHi;

    const float lim = fmaf(d2 + n2, 1.001f, 1e-4f);
    const float gLo = rho_d - edgeLo;
    const float gHi = edgeHi - rho_d;
    const bool lowOK  = (lo == 0) || ((gLo > 0.f) && (gLo * gLo > lim));
    const bool highOK = (hi == S) || ((gHi > 0.f) && (gHi * gHi > lim));

    __syncthreads();               // qs/ss reads done before next overwrite
    if (tid == 0) { flags[0] = 1; flags[1] = 1; }
    __syncthreads();
    if (!lowOK)  flags[0] = 0;
    if (!highOK) flags[1] = 0;
    __syncthreads();
    lowDoneB = flags[0];
    highDoneB = flags[1];
  }

  // ---- weights: reference's expanded form (unchanged, passing) ----
  int ii[3] = {i0, i1, i2};
  float w[3];
  #pragma unroll
  for (int k = 0; k < 3; ++k) {
    const float sx = sxyz[b * 3 * S + ii[k]];
    const float sy = sxyz[b * 3 * S + S + ii[k]];
    const float sz = sxyz[b * 3 * S + 2 * S + ii[k]];
    const float s2 = sx * sx + sy * sy + sz * sz;
    const float inner = bx * sx + by * sy + bz * sz;
    const float d = fmaxf((n2 + s2) - 2.f * inner, 0.f);
    w[k] = 1.f / (d + 1e-8f);
  }
  const float inv = 1.f / (w[0] + w[1] + w[2]);
  const size_t base = ((size_t)b * N + n) * 3;
  wgt[base + 0] = w[0] * inv;
  wgt[base + 1] = w[1] * inv;
  wgt[base + 2] = w[2] * inv;
  idx[base + 0] = ii[0];
  idx[base + 1] = ii[1];
  idx[base + 2] = ii[2];
}

// ---------------------------------------------------------------------------
// K1c: transpose conv_w -> Wt[c][o] for zproj's uniform loads.
// ---------------------------------------------------------------------------
__global__ __launch_bounds__(256) void wtrans_kernel(
    const float* __restrict__ cw, float* __restrict__ wt) {
  const int i = blockIdx.x * 256 + threadIdx.x;
  const int o = i / CIN;
  const int c = i - o * CIN;
  wt[c * CO + o] = cw[i];
}

// ---------------------------------------------------------------------------
// K2: Z[b, s, o] = sum_c Ws[o, c] * sparse_data[b, c, s]   (o-contiguous!)
// ---------------------------------------------------------------------------
__global__ __launch_bounds__(64) void zproj_kernel(
    const float* __restrict__ sdata, const float* __restrict__ wt,
    float* __restrict__ Z) {
  const int b = blockIdx.z;
  const int og = blockIdx.y;
  const int s = blockIdx.x * 64 + threadIdx.x;
  const float* __restrict__ xp = sdata + b * CS * S + s;
  const float* __restrict__ wp = wt + CD * CO + og * 16;

  float acc[16];
  #pragma unroll
  for (int i = 0; i < 16; ++i) acc[i] = 0.f;

  #pragma unroll 4
  for (int c = 0; c < CS; ++c) {
    const float xv = xp[c * S];
    #pragma unroll
    for (int i = 0; i < 16; ++i)
      acc[i] = fmaf(wp[c * CO + i], xv, acc[i]);
  }

  float4* zp = reinterpret_cast<float4*>(Z + (b * S + s) * CO + og * 16);
  #pragma unroll
  for (int i = 0; i < 4; ++i)
    zp[i] = make_float4(acc[4*i+0], acc[4*i+1], acc[4*i+2], acc[4*i+3]);
}

// ---------------------------------------------------------------------------
// K3: y[b, o, n] = sum_c Wd[o,c]*dense_data[b,c,n] + sum_k w_k * Z[b,idx_k,o]
// ---------------------------------------------------------------------------
__global__ __launch_bounds__(256) void ygemm_kernel(
    const float* __restrict__ ddata, const float* __restrict__ cw,
    const float* __restrict__ Z, const float* __restrict__ wgt,
    const int* __restrict__ idx, float* __restrict__ y) {
  const int b = blockIdx.y;
  const int n = blockIdx.x * 64 + (threadIdx.x & 63);
  const int rg = __builtin_amdgcn_readfirstlane(threadIdx.x >> 6);
  const float* __restrict__ xp = ddata + b * CD * N + n;
  const float* __restrict__ wp = cw + rg * 32 * CIN;

  float acc[32];
  #pragma unroll
  for (int i = 0; i < 32; ++i) acc[i] = 0.f;

  #pragma unroll 4
  for (int c = 0; c < CD; ++c) {
    const float xv = xp[c * N];
    #pragma unroll
    for (int i = 0; i < 32; ++i)
      acc[i] = fmaf(wp[i * CIN + c], xv, acc[i]);
  }

  const int pb = (b * N + n) * 3;
  #pragma unroll
  for (int k = 0; k < 3; ++k) {
    const float wk = wgt[pb + k];
    const int ik = idx[pb + k];
    const float4* zp =
        reinterpret_cast<const float4*>(Z + (b * S + ik) * CO + rg * 32);
    #pragma unroll
    for (int i = 0; i < 8; ++i) {
      float4 zv = zp[i];
      acc[4*i+0] = fmaf(wk, zv.x, acc[4*i+0]);
      acc[4*i+1] = fmaf(wk, zv.y, acc[4*i+1]);
      acc[4*i+2] = fmaf(wk, zv.z, acc[4*i+2]);
      acc[4*i+3] = fmaf(wk, zv.w, acc[4*i+3]);
    }
  }

  float* yp = y + b * CO * N + (rg * 32) * N + n;
  #pragma unroll
  for (int i = 0; i < 32; ++i) yp[i * N] = acc[i];
}

// ---------------------------------------------------------------------------
// K4: per-channel sum / sumsq over (B, N).
// ---------------------------------------------------------------------------
__global__ __launch_bounds__(256) void stats_kernel(
    const float* __restrict__ y, float* __restrict__ stats) {
  const int o = blockIdx.x;
  const int b = blockIdx.y;
  const float4* yp = reinterpret_cast<const float4*>(y + (b * CO + o) * N);
  float s = 0.f, sq = 0.f;
  for (int j = threadIdx.x; j < N / 4; j += 256) {
    float4 v = yp[j];
    s  += v.x + v.y + v.z + v.w;
    sq += v.x * v.x + v.y * v.y + v.z * v.z + v.w * v.w;
  }
  __shared__ float ls[256];
  __shared__ float lq[256];
  ls[threadIdx.x] = s;
  lq[threadIdx.x] = sq;
  __syncthreads();
  for (int st = 128; st > 0; st >>= 1) {
    if (threadIdx.x < (unsigned)st) {
      ls[threadIdx.x] += ls[threadIdx.x + st];
      lq[threadIdx.x] += lq[threadIdx.x + st];
    }
    __syncthreads();
  }
  if (threadIdx.x == 0) {
    atomicAdd(&stats[o], ls[0]);
    atomicAdd(&stats[CO + o], lq[0]);
  }
}

// ---------------------------------------------------------------------------
// K4b: fold BN stats into per-channel scale/shift.
// ---------------------------------------------------------------------------
__global__ void scaleshift_kernel(const float* __restrict__ stats,
                                  const float* __restrict__ gamma,
                                  const float* __restrict__ beta,
                                  float* __restrict__ ss) {
  const int o = threadIdx.x;
  const float invc = 1.f / (float)(B * N);
  const float m = stats[o] * invc;
  float v = stats[CO + o] * invc - m * m;
  v = fmaxf(v, 0.f);
  const float sc = gamma[o] / sqrtf(v + 1e-5f);
  ss[o] = sc;
  ss[CO + o] = beta[o] - m * sc;
}

// ---------------------------------------------------------------------------
// K5: in-place normalize + LeakyReLU(0.2) on d_out's y region (float4).
// ---------------------------------------------------------------------------
__global__ __launch_bounds__(256) void norm_kernel(float* __restrict__ y,
                                                   const float* __restrict__ ss) {
  const int i = blockIdx.x * 256 + threadIdx.x;
  const int o = (i >> 12) & (CO - 1);
  const float sc = ss[o];
  const float sh = ss[CO + o];
  float4* yp = reinterpret_cast<float4*>(y);
  float4 v = yp[i];
  float t;
  t = fmaf(v.x, sc, sh); v.x = fmaxf(t, 0.2f * t);
  t = fmaf(v.y, sc, sh); v.y = fmaxf(t, 0.2f * t);
  t = fmaf(v.z, sc, sh); v.z = fmaxf(t, 0.2f * t);
  t = fmaf(v.w, sc, sh); v.w = fmaxf(t, 0.2f * t);
  yp[i] = v;
}

// ---------------------------------------------------------------------------
extern "C" void kernel_launch(void* const* d_in, const int* in_sizes, int n_in,
                              void* d_out, int out_size, void* d_ws, size_t ws_size,
                              hipStream_t stream) {
  const float* dxyz  = (const float*)d_in[0];
  const float* sxyz  = (const float*)d_in[1];
  const float* ddata = (const float*)d_in[2];
  const float* sdata = (const float*)d_in[3];
  const float* cw    = (const float*)d_in[4];
  const float* gamma = (const float*)d_in[5];
  const float* beta  = (const float*)d_in[6];
  float* out = (float*)d_out;

  char* wsb = (char*)d_ws;
  // Persistent: wgt/idx. Radius-sort scratch aliases the Z region (dead
  // before zproj writes Z). Footprint: 14,157,824 B (unchanged).
  float*    wgt      = (float*)   (wsb);               //   786,432 B
  int*      idxb     = (int*)     (wsb + 786432);      //   786,432 B
  float*    Z        = (float*)   (wsb + 1572864);     // 8,388,608 B
  unsigned* rcnt_s   = (unsigned*)(wsb + 1572864);     // B*RB*4 = 4,096
  unsigned* rcnt_d   = (unsigned*)(wsb + 1576960);     // 4,096
  unsigned* rofs_s   = (unsigned*)(wsb + 1581056);     // 4,096
  unsigned* rcur_s   = (unsigned*)(wsb + 1585152);     // 4,096
  unsigned* rcur_d   = (unsigned*)(wsb + 1589248);     // 4,096
  int*      sortedS  = (int*)     (wsb + 1593344);     // 65,536
  float4*   sortedQ  = (float4*)  (wsb + 1658880);     // 262,144
  float4*   sortedDQ = (float4*)  (wsb + 1921024);     // 1,048,576 -> 2,969,600
  float*    wt       = (float*)   (wsb + 9961472);     // 196,608
  float*    stats    = (float*)   (wsb + 14155776);    // 1,024
  float*    ss       = (float*)   (wsb + 14156800);    // 1,024

  hipMemsetAsync(stats, 0, 2 * CO * sizeof(float), stream);
  hipMemsetAsync(rcnt_s, 0, 2 * B * RB * sizeof(unsigned), stream);

  rcount_s_kernel <<<B * S / 256, 256, 0, stream>>>(sxyz, rcnt_s);
  rcount_d_kernel <<<B * N / 256, 256, 0, stream>>>(dxyz, rcnt_d);
  rscan_kernel    <<<2 * B, RB, 0, stream>>>(rcnt_s, rcnt_d, rofs_s, rcur_s, rcur_d);
  rscatter_s_kernel<<<B * S / 256, 256, 0, stream>>>(sxyz, rcur_s, sortedS, sortedQ);
  rscatter_d_kernel<<<B * N / 256, 256, 0, stream>>>(dxyz, rcur_d, sortedDQ);
  knn_rho_kernel  <<<dim3(N / KT, B), KT, 0, stream>>>(sortedDQ, sxyz, rofs_s,
                                                       sortedS, sortedQ, wgt, idxb);

  wtrans_kernel   <<<CO * CIN / 256, 256, 0, stream>>>(cw, wt);
  zproj_kernel    <<<dim3(S / 64, CO / 16, B), 64, 0, stream>>>(sdata, wt, Z);
  ygemm_kernel    <<<dim3(N / 64, B), 256, 0, stream>>>(ddata, cw, Z, wgt, idxb, out);
  stats_kernel    <<<dim3(CO, B), 256, 0, stream>>>(out, stats);
  scaleshift_kernel<<<1, 128, 0, stream>>>(stats, gamma, beta, ss);
  norm_kernel     <<<(B * CO * N / 4) / 256, 256, 0, stream>>>(out, ss);

  hipMemcpyAsync(out + (size_t)B * CO * N, dxyz, (size_t)B * 3 * N * sizeof(float),
                 hipMemcpyDeviceToDevice, stream);
}

// Round 13
// 285.088 us; speedup vs baseline: 4.5140x; 1.4203x over previous
//
#include <hip/hip_runtime.h>

// Problem constants (fixed shapes from setup_inputs)
constexpr int B  = 4;
constexpr int N  = 16384;   // dense points
constexpr int S  = 4096;    // sparse points
constexpr int CD = 128;     // dense feature channels
constexpr int CS = 256;     // sparse feature channels
constexpr int CO = 128;     // output channels
constexpr int CIN = CD + CS; // 384

// Radius binning. N(0,1)^3: rho < ~5.0 << 6.6.
constexpr int   RB    = 256;
constexpr float RBW   = 6.6f / 256.0f;
constexpr float RBINV = 256.0f / 6.6f;

__device__ __forceinline__ int rbin(float rho) {
  return min(RB - 1, (int)(rho * RBINV));
}

// Fixed rho-window: W candidates total, scanned as NCW chunks of WCH by
// independent blocks (R5's proven 4096-wave shape). Certification at merge
// makes the result exact regardless of window adequacy.
constexpr int W   = 2048;
constexpr int NCW = 4;
constexpr int WCH = W / NCW;  // 512

// Lexicographic (t, idx) top-3 insert — proven (R9-R12 pass) to match the
// reference selection and to be independent of candidate arrival order.
__device__ __forceinline__ bool lex_lt(float x, int sg, float d, int i) {
  return (x < d) | ((x == d) & (sg < i));
}
__device__ __forceinline__ void insert3lex(float& d0, float& d1, float& d2,
                                           int& i0, int& i1, int& i2,
                                           float x, int sg) {
  const bool lt2 = lex_lt(x, sg, d2, i2);
  const bool lt1 = lex_lt(x, sg, d1, i1);
  const bool lt0 = lex_lt(x, sg, d0, i0);
  i2 = lt1 ? i1 : (lt2 ? sg : i2);
  i1 = lt0 ? i0 : (lt1 ? sg : i1);
  i0 = lt0 ? sg : i0;
  d2 = fminf(fmaxf(x, d1), d2);
  d1 = __builtin_amdgcn_fmed3f(x, d0, d1);
  d0 = fminf(x, d0);
}

// ---------------------------------------------------------------------------
// R1: radius-bin histograms (verbatim R12, passing).
// ---------------------------------------------------------------------------
__global__ __launch_bounds__(256) void rcount_s_kernel(
    const float* __restrict__ sxyz, unsigned* __restrict__ rcnt) {
  const int gid = blockIdx.x * 256 + threadIdx.x;
  const int b = gid >> 12;
  const int s = gid & (S - 1);
  const float sx = sxyz[b * 3 * S + s];
  const float sy = sxyz[b * 3 * S + S + s];
  const float sz = sxyz[b * 3 * S + 2 * S + s];
  const float s2 = fmaf(sx, sx, fmaf(sy, sy, sz * sz));
  atomicAdd(&rcnt[b * RB + rbin(sqrtf(s2))], 1u);
}

__global__ __launch_bounds__(256) void rcount_d_kernel(
    const float* __restrict__ dxyz, unsigned* __restrict__ rcnt) {
  const int gid = blockIdx.x * 256 + threadIdx.x;
  const int b = gid >> 14;
  const int n = gid & (N - 1);
  const float x = dxyz[b * 3 * N + n];
  const float y = dxyz[b * 3 * N + N + n];
  const float z = dxyz[b * 3 * N + 2 * N + n];
  const float n2 = x * x + y * y + z * z;
  atomicAdd(&rcnt[b * RB + rbin(sqrtf(n2))], 1u);
}

// ---------------------------------------------------------------------------
// R2: deterministic exclusive scan over 256 bins (verbatim R12).
// ---------------------------------------------------------------------------
__global__ __launch_bounds__(256) void rscan_kernel(
    const unsigned* __restrict__ rcnt_s, const unsigned* __restrict__ rcnt_d,
    unsigned* __restrict__ rofs_s, unsigned* __restrict__ rcur_s,
    unsigned* __restrict__ rcur_d) {
  const int which = blockIdx.x >> 2;
  const int b = blockIdx.x & 3;
  const unsigned* __restrict__ C = (which ? rcnt_d : rcnt_s) + b * RB;
  const int t = threadIdx.x;
  __shared__ unsigned sc[RB];
  const unsigned v = C[t];
  sc[t] = v;
  __syncthreads();
  for (int off = 1; off < RB; off <<= 1) {
    unsigned u = (t >= off) ? sc[t - off] : 0u;
    __syncthreads();
    sc[t] += u;
    __syncthreads();
  }
  const unsigned ex = sc[t] - v;
  if (which == 0) { rofs_s[b * RB + t] = ex; rcur_s[b * RB + t] = ex; }
  else            { rcur_d[b * RB + t] = ex; }
}

// ---------------------------------------------------------------------------
// R3s/R3d: scatter into rho-bin order (verbatim R12; within-bin order is
// atomic-nondeterministic — output-invariant by lex insert + exactness).
// ---------------------------------------------------------------------------
__global__ __launch_bounds__(256) void rscatter_s_kernel(
    const float* __restrict__ sxyz, unsigned* __restrict__ rcur_s,
    int* __restrict__ sortedS, float4* __restrict__ sortedQ) {
  const int gid = blockIdx.x * 256 + threadIdx.x;
  const int b = gid >> 12;
  const int s = gid & (S - 1);
  const float sx = sxyz[b * 3 * S + s];
  const float sy = sxyz[b * 3 * S + S + s];
  const float sz = sxyz[b * 3 * S + 2 * S + s];
  const float s2 = fmaf(sx, sx, fmaf(sy, sy, sz * sz));
  const int bin = rbin(sqrtf(s2));
  const unsigned pos = atomicAdd(&rcur_s[b * RB + bin], 1u);
  sortedS[b * S + pos] = s;
  sortedQ[b * S + pos] = make_float4(-2.f * sx, -2.f * sy, -2.f * sz, s2);
}

__global__ __launch_bounds__(256) void rscatter_d_kernel(
    const float* __restrict__ dxyz, unsigned* __restrict__ rcur_d,
    float4* __restrict__ sortedDQ) {
  const int gid = blockIdx.x * 256 + threadIdx.x;
  const int b = gid >> 14;
  const int n = gid & (N - 1);
  const float x = dxyz[b * 3 * N + n];
  const float y = dxyz[b * 3 * N + N + n];
  const float z = dxyz[b * 3 * N + 2 * N + n];
  const float n2 = x * x + y * y + z * z;
  const int bin = rbin(sqrtf(n2));
  const unsigned pos = atomicAdd(&rcur_d[b * RB + bin], 1u);
  sortedDQ[b * N + pos] = make_float4(x, y, z, __int_as_float(n));
}

// ---------------------------------------------------------------------------
// K1a: window partials in the R5 execution shape. Block = (point-group g,
// chunk nc, batch b): stages its fixed 512-candidate chunk of the group's
// rho-window into LDS, then every thread runs a compile-time unrolled
// wave-uniform broadcast scan. 1024 blocks x 4 waves = 4096 waves (the
// occupancy regime where this loop measured 88-100% VALUBusy in R5/R7).
// ---------------------------------------------------------------------------
__global__ __launch_bounds__(256) void knn_part_kernel(
    const float4* __restrict__ sortedDQ, const unsigned* __restrict__ rofs_s,
    const int* __restrict__ sortedS, const float4* __restrict__ sortedQ,
    float* __restrict__ pbuf) {
  __shared__ float4 qs[WCH];
  __shared__ int    ssi[WCH];
  __shared__ int    sh_winLo;
  const int b  = blockIdx.z;
  const int nc = blockIdx.y;
  const int g  = blockIdx.x;
  const int tid = threadIdx.x;

  if (tid == 0) {
    const float4 mid = sortedDQ[b * N + g * 256 + 128];
    const float rho =
        sqrtf(mid.x * mid.x + mid.y * mid.y + mid.z * mid.z);
    const int c = (int)rofs_s[b * RB + rbin(rho)];
    sh_winLo = min(max(c - W / 2, 0), S - W);
  }
  __syncthreads();
  const int lo = sh_winLo + nc * WCH;

  for (int u = tid; u < WCH; u += 256) {   // coalesced stage
    qs[u]  = sortedQ[b * S + lo + u];
    ssi[u] = sortedS[b * S + lo + u];
  }
  __syncthreads();

  const float4 dq = sortedDQ[b * N + g * 256 + tid];
  const float bx = dq.x, by = dq.y, bz = dq.z;
  float d0 = 1e30f, d1 = 1e30f, d2 = 1e30f;
  int i0 = 0, i1 = 0, i2 = 0;

  #pragma unroll 4
  for (int j = 0; j < WCH; ++j) {          // wave-uniform LDS broadcast
    const float4 q = qs[j];
    const float x = fmaf(q.x, bx, fmaf(q.y, by, fmaf(q.z, bz, q.w)));
    insert3lex(d0, d1, d2, i0, i1, i2, x, ssi[j]);
  }

  float* pp = pbuf + (((size_t)nc * B + b) * N + g * 256 + tid) * 6;
  pp[0] = d0; pp[1] = __int_as_float(i0);
  pp[2] = d1; pp[3] = __int_as_float(i1);
  pp[4] = d2; pp[5] = __int_as_float(i2);
}

// ---------------------------------------------------------------------------
// K1b: merge the NCW partials (lex, arrival-independent), certify with the
// R12-verbatim bin-edge bound, brute-rescan on failure (exact, rare), then
// compute weights in the reference's expanded form (verbatim, passing).
// ---------------------------------------------------------------------------
__global__ __launch_bounds__(256) void knn_merge_rho_kernel(
    const float* __restrict__ pbuf, const float4* __restrict__ sortedDQ,
    const unsigned* __restrict__ rofs_s, const int* __restrict__ sortedS,
    const float4* __restrict__ sortedQ, const float* __restrict__ sxyz,
    float* __restrict__ wgt, int* __restrict__ idx) {
  const int gid = blockIdx.x * 256 + threadIdx.x;  // = b*N + sorted pos
  const int b = gid >> 14;
  const int pos = gid & (N - 1);
  const int g = pos >> 8;
  const float4 dq = sortedDQ[gid];
  const float bx = dq.x, by = dq.y, bz = dq.z;
  const int n = __float_as_int(dq.w);
  const float n2 = bx * bx + by * by + bz * bz;
  const float rho_d = sqrtf(n2);

  float d0 = 1e30f, d1 = 1e30f, d2 = 1e30f;
  int i0 = 0, i1 = 0, i2 = 0;
  #pragma unroll
  for (int nc = 0; nc < NCW; ++nc) {
    const float* pp = pbuf + (((size_t)nc * B + b) * N + pos) * 6;
    insert3lex(d0, d1, d2, i0, i1, i2, pp[0], __float_as_int(pp[1]));
    insert3lex(d0, d1, d2, i0, i1, i2, pp[2], __float_as_int(pp[3]));
    insert3lex(d0, d1, d2, i0, i1, i2, pp[4], __float_as_int(pp[5]));
  }

  // recompute winLo exactly as knn_part (same inputs -> same value)
  const float4 mid = sortedDQ[b * N + g * 256 + 128];
  const float rhom = sqrtf(mid.x * mid.x + mid.y * mid.y + mid.z * mid.z);
  const int c = (int)rofs_s[b * RB + rbin(rhom)];
  const int winLo = min(max(c - W / 2, 0), S - W);
  const int winHi = winLo + W;

  const float4* __restrict__ Q = sortedQ + b * S;
  const int* __restrict__ SS = sortedS + b * S;
  const float lim = fmaf(d2 + n2, 1.001f, 1e-4f);
  bool ok = true;
  if (winLo > 0) {  // unscanned below: bins <= bin(Q[winLo]) -> rho < edge
    const float edgeLo = (float)(rbin(sqrtf(Q[winLo].w)) + 1) * RBW;
    const float gLo = rho_d - edgeLo;
    ok = (gLo > 0.f) && (gLo * gLo > lim);
  }
  if (ok && winHi < S) {  // unscanned above: bins >= bin(Q[winHi-1])
    const float edgeHi = (float)rbin(sqrtf(Q[winHi - 1].w)) * RBW;
    const float gHi = edgeHi - rho_d;
    ok = (gHi > 0.f) && (gHi * gHi > lim);
  }
  if (!ok) {  // exact fallback: full scan (rare)
    d0 = d1 = d2 = 1e30f;
    i0 = i1 = i2 = 0;
    for (int j = 0; j < S; ++j) {
      const float4 q = Q[j];
      const float x = fmaf(q.x, bx, fmaf(q.y, by, fmaf(q.z, bz, q.w)));
      insert3lex(d0, d1, d2, i0, i1, i2, x, SS[j]);
    }
  }

  // ---- weights: reference's expanded form (verbatim, passing) ----
  int ii[3] = {i0, i1, i2};
  float w[3];
  #pragma unroll
  for (int k = 0; k < 3; ++k) {
    const float sx = sxyz[b * 3 * S + ii[k]];
    const float sy = sxyz[b * 3 * S + S + ii[k]];
    const float sz = sxyz[b * 3 * S + 2 * S + ii[k]];
    const float s2 = sx * sx + sy * sy + sz * sz;
    const float inner = bx * sx + by * sy + bz * sz;
    const float d = fmaxf((n2 + s2) - 2.f * inner, 0.f);
    w[k] = 1.f / (d + 1e-8f);
  }
  const float inv = 1.f / (w[0] + w[1] + w[2]);
  const size_t base = ((size_t)b * N + n) * 3;
  wgt[base + 0] = w[0] * inv;
  wgt[base + 1] = w[1] * inv;
  wgt[base + 2] = w[2] * inv;
  idx[base + 0] = ii[0];
  idx[base + 1] = ii[1];
  idx[base + 2] = ii[2];
}

// ---------------------------------------------------------------------------
// K1c: transpose conv_w -> Wt[c][o] for zproj's uniform loads.
// ---------------------------------------------------------------------------
__global__ __launch_bounds__(256) void wtrans_kernel(
    const float* __restrict__ cw, float* __restrict__ wt) {
  const int i = blockIdx.x * 256 + threadIdx.x;
  const int o = i / CIN;
  const int c = i - o * CIN;
  wt[c * CO + o] = cw[i];
}

// ---------------------------------------------------------------------------
// K2: Z[b, s, o] = sum_c Ws[o, c] * sparse_data[b, c, s]   (o-contiguous!)
// ---------------------------------------------------------------------------
__global__ __launch_bounds__(64) void zproj_kernel(
    const float* __restrict__ sdata, const float* __restrict__ wt,
    float* __restrict__ Z) {
  const int b = blockIdx.z;
  const int og = blockIdx.y;
  const int s = blockIdx.x * 64 + threadIdx.x;
  const float* __restrict__ xp = sdata + b * CS * S + s;
  const float* __restrict__ wp = wt + CD * CO + og * 16;

  float acc[16];
  #pragma unroll
  for (int i = 0; i < 16; ++i) acc[i] = 0.f;

  #pragma unroll 4
  for (int c = 0; c < CS; ++c) {
    const float xv = xp[c * S];
    #pragma unroll
    for (int i = 0; i < 16; ++i)
      acc[i] = fmaf(wp[c * CO + i], xv, acc[i]);
  }

  float4* zp = reinterpret_cast<float4*>(Z + (b * S + s) * CO + og * 16);
  #pragma unroll
  for (int i = 0; i < 4; ++i)
    zp[i] = make_float4(acc[4*i+0], acc[4*i+1], acc[4*i+2], acc[4*i+3]);
}

// ---------------------------------------------------------------------------
// K3: y[b, o, n] = sum_c Wd[o,c]*dense_data[b,c,n] + sum_k w_k * Z[b,idx_k,o]
// ---------------------------------------------------------------------------
__global__ __launch_bounds__(256) void ygemm_kernel(
    const float* __restrict__ ddata, const float* __restrict__ cw,
    const float* __restrict__ Z, const float* __restrict__ wgt,
    const int* __restrict__ idx, float* __restrict__ y) {
  const int b = blockIdx.y;
  const int n = blockIdx.x * 64 + (threadIdx.x & 63);
  const int rg = __builtin_amdgcn_readfirstlane(threadIdx.x >> 6);
  const float* __restrict__ xp = ddata + b * CD * N + n;
  const float* __restrict__ wp = cw + rg * 32 * CIN;

  float acc[32];
  #pragma unroll
  for (int i = 0; i < 32; ++i) acc[i] = 0.f;

  #pragma unroll 4
  for (int c = 0; c < CD; ++c) {
    const float xv = xp[c * N];
    #pragma unroll
    for (int i = 0; i < 32; ++i)
      acc[i] = fmaf(wp[i * CIN + c], xv, acc[i]);
  }

  const int pb = (b * N + n) * 3;
  #pragma unroll
  for (int k = 0; k < 3; ++k) {
    const float wk = wgt[pb + k];
    const int ik = idx[pb + k];
    const float4* zp =
        reinterpret_cast<const float4*>(Z + (b * S + ik) * CO + rg * 32);
    #pragma unroll
    for (int i = 0; i < 8; ++i) {
      float4 zv = zp[i];
      acc[4*i+0] = fmaf(wk, zv.x, acc[4*i+0]);
      acc[4*i+1] = fmaf(wk, zv.y, acc[4*i+1]);
      acc[4*i+2] = fmaf(wk, zv.z, acc[4*i+2]);
      acc[4*i+3] = fmaf(wk, zv.w, acc[4*i+3]);
    }
  }

  float* yp = y + b * CO * N + (rg * 32) * N + n;
  #pragma unroll
  for (int i = 0; i < 32; ++i) yp[i * N] = acc[i];
}

// ---------------------------------------------------------------------------
// K4: per-channel sum / sumsq over (B, N).
// ---------------------------------------------------------------------------
__global__ __launch_bounds__(256) void stats_kernel(
    const float* __restrict__ y, float* __restrict__ stats) {
  const int o = blockIdx.x;
  const int b = blockIdx.y;
  const float4* yp = reinterpret_cast<const float4*>(y + (b * CO + o) * N);
  float s = 0.f, sq = 0.f;
  for (int j = threadIdx.x; j < N / 4; j += 256) {
    float4 v = yp[j];
    s  += v.x + v.y + v.z + v.w;
    sq += v.x * v.x + v.y * v.y + v.z * v.z + v.w * v.w;
  }
  __shared__ float ls[256];
  __shared__ float lq[256];
  ls[threadIdx.x] = s;
  lq[threadIdx.x] = sq;
  __syncthreads();
  for (int st = 128; st > 0; st >>= 1) {
    if (threadIdx.x < (unsigned)st) {
      ls[threadIdx.x] += ls[threadIdx.x + st];
      lq[threadIdx.x] += lq[threadIdx.x + st];
    }
    __syncthreads();
  }
  if (threadIdx.x == 0) {
    atomicAdd(&stats[o], ls[0]);
    atomicAdd(&stats[CO + o], lq[0]);
  }
}

// ---------------------------------------------------------------------------
// K4b: fold BN stats into per-channel scale/shift.
// ---------------------------------------------------------------------------
__global__ void scaleshift_kernel(const float* __restrict__ stats,
                                  const float* __restrict__ gamma,
                                  const float* __restrict__ beta,
                                  float* __restrict__ ss) {
  const int o = threadIdx.x;
  const float invc = 1.f / (float)(B * N);
  const float m = stats[o] * invc;
  float v = stats[CO + o] * invc - m * m;
  v = fmaxf(v, 0.f);
  const float sc = gamma[o] / sqrtf(v + 1e-5f);
  ss[o] = sc;
  ss[CO + o] = beta[o] - m * sc;
}

// ---------------------------------------------------------------------------
// K5: in-place normalize + LeakyReLU(0.2) on d_out's y region (float4).
// ---------------------------------------------------------------------------
__global__ __launch_bounds__(256) void norm_kernel(float* __restrict__ y,
                                                   const float* __restrict__ ss) {
  const int i = blockIdx.x * 256 + threadIdx.x;
  const int o = (i >> 12) & (CO - 1);
  const float sc = ss[o];
  const float sh = ss[CO + o];
  float4* yp = reinterpret_cast<float4*>(y);
  float4 v = yp[i];
  float t;
  t = fmaf(v.x, sc, sh); v.x = fmaxf(t, 0.2f * t);
  t = fmaf(v.y, sc, sh); v.y = fmaxf(t, 0.2f * t);
  t = fmaf(v.z, sc, sh); v.z = fmaxf(t, 0.2f * t);
  t = fmaf(v.w, sc, sh); v.w = fmaxf(t, 0.2f * t);
  yp[i] = v;
}

// ---------------------------------------------------------------------------
extern "C" void kernel_launch(void* const* d_in, const int* in_sizes, int n_in,
                              void* d_out, int out_size, void* d_ws, size_t ws_size,
                              hipStream_t stream) {
  const float* dxyz  = (const float*)d_in[0];
  const float* sxyz  = (const float*)d_in[1];
  const float* ddata = (const float*)d_in[2];
  const float* sdata = (const float*)d_in[3];
  const float* cw    = (const float*)d_in[4];
  const float* gamma = (const float*)d_in[5];
  const float* beta  = (const float*)d_in[6];
  float* out = (float*)d_out;

  char* wsb = (char*)d_ws;
  // Persistent: wgt/idx. Sort scratch + partial buffers alias the Z region
  // (all dead before zproj writes Z). Footprint: 14,157,824 B (unchanged).
  float*    wgt      = (float*)   (wsb);               //   786,432 B
  int*      idxb     = (int*)     (wsb + 786432);      //   786,432 B
  float*    Z        = (float*)   (wsb + 1572864);     // 8,388,608 B
  unsigned* rcnt_s   = (unsigned*)(wsb + 1572864);     // 4,096
  unsigned* rcnt_d   = (unsigned*)(wsb + 1576960);     // 4,096
  unsigned* rofs_s   = (unsigned*)(wsb + 1581056);     // 4,096
  unsigned* rcur_s   = (unsigned*)(wsb + 1585152);     // 4,096
  unsigned* rcur_d   = (unsigned*)(wsb + 1589248);     // 4,096
  int*      sortedS  = (int*)     (wsb + 1593344);     // 65,536
  float4*   sortedQ  = (float4*)  (wsb + 1658880);     // 262,144
  float4*   sortedDQ = (float4*)  (wsb + 1921024);     // 1,048,576
  float*    pbuf     = (float*)   (wsb + 2969600);     // NCW*B*N*6*4 = 6,291,456 -> 9,261,056
  float*    wt       = (float*)   (wsb + 9961472);     // 196,608
  float*    stats    = (float*)   (wsb + 14155776);    // 1,024
  float*    ss       = (float*)   (wsb + 14156800);    // 1,024

  hipMemsetAsync(stats, 0, 2 * CO * sizeof(float), stream);
  hipMemsetAsync(rcnt_s, 0, 2 * B * RB * sizeof(unsigned), stream);

  rcount_s_kernel  <<<B * S / 256, 256, 0, stream>>>(sxyz, rcnt_s);
  rcount_d_kernel  <<<B * N / 256, 256, 0, stream>>>(dxyz, rcnt_d);
  rscan_kernel     <<<2 * B, RB, 0, stream>>>(rcnt_s, rcnt_d, rofs_s, rcur_s, rcur_d);
  rscatter_s_kernel<<<B * S / 256, 256, 0, stream>>>(sxyz, rcur_s, sortedS, sortedQ);
  rscatter_d_kernel<<<B * N / 256, 256, 0, stream>>>(dxyz, rcur_d, sortedDQ);
  knn_part_kernel  <<<dim3(N / 256, NCW, B), 256, 0, stream>>>(
      sortedDQ, rofs_s, sortedS, sortedQ, pbuf);
  knn_merge_rho_kernel<<<B * N / 256, 256, 0, stream>>>(
      pbuf, sortedDQ, rofs_s, sortedS, sortedQ, sxyz, wgt, idxb);

  wtrans_kernel   <<<CO * CIN / 256, 256, 0, stream>>>(cw, wt);
  zproj_kernel    <<<dim3(S / 64, CO / 16, B), 64, 0, stream>>>(sdata, wt, Z);
  ygemm_kernel    <<<dim3(N / 64, B), 256, 0, stream>>>(ddata, cw, Z, wgt, idxb, out);
  stats_kernel    <<<dim3(CO, B), 256, 0, stream>>>(out, stats);
  scaleshift_kernel<<<1, 128, 0, stream>>>(stats, gamma, beta, ss);
  norm_kernel     <<<(B * CO * N / 4) / 256, 256, 0, stream>>>(out, ss);

  hipMemcpyAsync(out + (size_t)B * CO * N, dxyz, (size_t)B * 3 * N * sizeof(float),
                 hipMemcpyDeviceToDevice, stream);
}